// Round 15
// baseline (353.103 us; speedup 1.0000x reference)
//
#include <hip/hip_runtime.h>
#include <math.h>

namespace {
constexpr int NIN   = 32;
constexpr int H_    = 14;
constexpr int CIN   = 8;
constexpr int C_    = 32;
constexpr int COUT  = 16;
constexpr int R_    = 288;
constexpr int W_    = 12;
constexpr int NITER = 3;
constexpr int CH    = 32;              // r per chunk
constexpr int NCH   = 9;               // 288/32
constexpr int NTILE = 9;               // tiles per persistent block (9216/1024)
constexpr int NBLK  = 1024;            // 4 blocks/CU x 256 CUs
constexpr size_t XSUB = (size_t)NIN * H_ * H_ * CIN;   // x stride per batch elem
}

typedef unsigned int u32;
typedef const __attribute__((address_space(1))) u32* as1_u32p;
typedef __attribute__((address_space(3))) u32* as3_u32p;

__device__ __forceinline__ void async_copy16(const void* g, void* l) {
    __builtin_amdgcn_global_load_lds((as1_u32p)g, (as3_u32p)l, 16, 0, 0);
}
__device__ __forceinline__ float dot4(const float4 a, const float4 b) {
    return fmaf(a.x, b.x, fmaf(a.y, b.y, fmaf(a.z, b.z, a.w * b.w)));
}
// VALU-pipe cross-lane ops (DPP) — keep traffic off the DS pipe.
__device__ __forceinline__ float dpp_add_xor1(float v) {
    int t = __builtin_amdgcn_update_dpp(0, __float_as_int(v), 0xB1, 0xF, 0xF, true);
    return v + __int_as_float(t);
}
__device__ __forceinline__ float dpp_add_xor2(float v) {
    int t = __builtin_amdgcn_update_dpp(0, __float_as_int(v), 0x4E, 0xF, 0xF, true);
    return v + __int_as_float(t);
}
__device__ __forceinline__ float dpp_add_shr4(float v) {
    int t = __builtin_amdgcn_update_dpp(0, __float_as_int(v), 0x114, 0xF, 0xF, true);
    return v + __int_as_float(t);
}
__device__ __forceinline__ float dpp_add_shr8(float v) {
    int t = __builtin_amdgcn_update_dpp(0, __float_as_int(v), 0x118, 0xF, 0xF, true);
    return v + __int_as_float(t);
}
template <int CTRL>
__device__ __forceinline__ float dpp_bc(float v) {   // quad broadcast (mov)
    return __int_as_float(
        __builtin_amdgcn_update_dpp(0, __float_as_int(v), CTRL, 0xF, 0xF, true));
}

// PERSISTENT version of R12 (the 153 us best): 1024 blocks (4/CU, the LDS
// residency limit), each processing 9 tiles of (c, b-pair, p, q). Rationale:
// R12/R13/R14 all pinned at ~155 us with occupancy stuck at ~31% while DS,
// LDS and barrier cuts did nothing — the binding constraint is block
// lifecycle (9216 x ~11us blocks never hold 4-block residency). Persistence
// pins residency and adds CROSS-TILE prefetch: during tile t's chunk-8
// compute we stage tile t+1's chunk 0 (wbuf parity runs continuously, 9 odd)
// and prefetch its x — the drain lands at the routing phase's first barrier,
// covered by chunk-8 + iter-0 compute. Zero tail: 9216 = 1024 x 9.
// Everything else is R12 verbatim (quad-exchange x path, DPP reductions,
// 2-barrier routing). Lessons: 256-thr blocks (R6/R10); no forced waves/EU
// (R4); priors fp32 (R2); cross-lane on DPP (R9/R11); non-redundant x (R12).
__global__ __launch_bounds__(256)
void caps_routeF(const float* __restrict__ x,
                 const float* __restrict__ rw,
                 float* __restrict__ out)
{
    __shared__ float4 wbuf[2][1024];   // [buf][i(8)][cr(32)][og(4)] 16 KB each
    __shared__ float  sRed[4][2][16];  // [wave][local sub][o]
    __shared__ float  redE[4][2];      // [wave][local sub]
    __shared__ float  vS[4][16];       // [sub][o]

    const int tid = threadIdx.x;
    const int og   = tid & 3;
    const int rl   = tid >> 2;     // 0..63
    const int cr   = rl & 31;      // chunk-local r
    const int sh   = rl >> 5;      // wave-uniform
    const int lane = tid & 63;
    const int wv   = tid >> 6;
    const int sA   = sh * 2;       // first sub of this thread's pair

    // per-lane x sub-offset: lane og covers (sub sA + (og>>1), half og&1)
    const size_t xlaneoff = (size_t)(sA + (og >> 1)) * XSUB + (og & 1) * 4;

    // tile ctx (current and next)
    const float*  xqC; const float4* rwcC; int pC, qC, b0C, cC;
    const float*  xqN; const float4* rwcN; int pN, qN, b0N, cN;

    auto mk = [&](int tile, const float*& xq_, const float4*& rwc_,
                  int& p_, int& q_, int& b0_, int& c_) {
        const int pq = tile % 144;
        p_  = pq / W_;  q_ = pq % W_;
        b0_ = ((tile / 144) & 1) * 4;
        c_  = tile / 288;
        xq_  = x + (size_t)b0_ * XSUB + xlaneoff;
        rwc_ = (const float4*)(rw + (size_t)c_ * R_ * CIN * COUT);
    };

    float4 xv;                     // this lane's single x float4 for a chunk
    auto xld = [&](const float* xq_, int p_, int q_, int k) {
        const int r  = k * CH + cr;
        const int n  = r / 9, rem = r - n * 9;
        const int kh = rem / 3, kw = rem - kh * 3;
        xv = *(const float4*)(xq_ + ((n * H_ + (p_ + kh)) * H_ + (q_ + kw)) * CIN);
    };

    auto stage = [&](const float4* rwc_, int k, int buf) {
        // slot s = t*256+tid -> [ii=s>>7][wcr=(s>>2)&31][wog=s&3];
        // global f4 = wcr*32 + ii*4 + wog (chunk base k*1024 f4)
        const float4* gchunk = rwc_ + (size_t)k * (CH * 32);
        #pragma unroll
        for (int t = 0; t < 4; ++t) {
            const int s   = t * 256 + tid;
            const int ii  = s >> 7;
            const int wcr = (s >> 2) & 31;
            async_copy16(gchunk + (wcr * 32 + ii * 4 + (s & 3)),
                         (char*)&wbuf[buf][0] + (t * 256 + (tid & 192)) * 16);
        }
    };

    const int blk = blockIdx.x;
    mk(blk, xqC, rwcC, pC, qC, b0C, cC);
    xld(xqC, pC, qC, 0);
    stage(rwcC, 0, 0);
    int gbuf = 0;                  // continuous parity across tiles (9 odd)

    float4 acc[NCH][2];

    for (int t = 0; t < NTILE; ++t) {
        const bool hasNext = (t + 1 < NTILE);

        #pragma unroll
        for (int k = 0; k < NCH; ++k) {
            __syncthreads();           // stage/xld for chunk k drained
            if (k + 1 < NCH) {
                stage(rwcC, k + 1, gbuf ^ 1);
            } else if (hasNext) {      // cross-tile prefetch of chunk 0
                mk(blk + NBLK * (t + 1), xqN, rwcN, pN, qN, b0N, cN);
                stage(rwcN, 0, gbuf ^ 1);
            }
            const float4* wb = &wbuf[gbuf][0];
            // og-quad exchange: fA = sub sA channels 0..7, fB = sub sA+1
            const float4 cur = xv;
            float fA[8], fB[8];
            fA[0] = dpp_bc<0x00>(cur.x); fA[1] = dpp_bc<0x00>(cur.y);
            fA[2] = dpp_bc<0x00>(cur.z); fA[3] = dpp_bc<0x00>(cur.w);
            fA[4] = dpp_bc<0x55>(cur.x); fA[5] = dpp_bc<0x55>(cur.y);
            fA[6] = dpp_bc<0x55>(cur.z); fA[7] = dpp_bc<0x55>(cur.w);
            fB[0] = dpp_bc<0xAA>(cur.x); fB[1] = dpp_bc<0xAA>(cur.y);
            fB[2] = dpp_bc<0xAA>(cur.z); fB[3] = dpp_bc<0xAA>(cur.w);
            fB[4] = dpp_bc<0xFF>(cur.x); fB[5] = dpp_bc<0xFF>(cur.y);
            fB[6] = dpp_bc<0xFF>(cur.z); fB[7] = dpp_bc<0xFF>(cur.w);
            if (k + 1 < NCH) xld(xqC, pC, qC, k + 1);       // WAR on xv cleared
            else if (hasNext) xld(xqN, pN, qN, 0);
            float4 a0 = make_float4(0.f, 0.f, 0.f, 0.f);
            float4 a1 = make_float4(0.f, 0.f, 0.f, 0.f);
            #pragma unroll
            for (int i = 0; i < 8; ++i) {
                const float4 wv4 = wb[i * 128 + cr * 4 + og];   // conflict-free b128
                a0.x = fmaf(fA[i], wv4.x, a0.x);  a1.x = fmaf(fB[i], wv4.x, a1.x);
                a0.y = fmaf(fA[i], wv4.y, a0.y);  a1.y = fmaf(fB[i], wv4.y, a1.y);
                a0.z = fmaf(fA[i], wv4.z, a0.z);  a1.z = fmaf(fB[i], wv4.z, a1.z);
                a0.w = fmaf(fA[i], wv4.w, a0.w);  a1.w = fmaf(fB[i], wv4.w, a1.w);
            }
            acc[k][0] = a0;  acc[k][1] = a1;
            gbuf ^= 1;
        }

        float lgA[NCH], lgB[NCH];
        #pragma unroll
        for (int j = 0; j < NCH; ++j) { lgA[j] = 0.f; lgB[j] = 0.f; }

        for (int it = 0; it < NITER; ++it) {
            float4 s0 = make_float4(0.f, 0.f, 0.f, 0.f);
            float4 s1 = make_float4(0.f, 0.f, 0.f, 0.f);
            float se0 = 0.f, se1 = 0.f;

            if (it == 0) {
                #pragma unroll
                for (int j = 0; j < NCH; ++j) {
                    s0.x += acc[j][0].x;  s1.x += acc[j][1].x;
                    s0.y += acc[j][0].y;  s1.y += acc[j][1].y;
                    s0.z += acc[j][0].z;  s1.z += acc[j][1].z;
                    s0.w += acc[j][0].w;  s1.w += acc[j][1].w;
                }
            } else {
                const float4 v0 = *(const float4*)&vS[sA][og * 4];
                const float4 v1 = *(const float4*)&vS[sA + 1][og * 4];
                #pragma unroll
                for (int j = 0; j < NCH; ++j) {
                    float d0 = dot4(acc[j][0], v0);
                    float d1 = dot4(acc[j][1], v1);
                    d0 = dpp_add_xor1(d0);  d1 = dpp_add_xor1(d1);   // VALU
                    d0 = dpp_add_xor2(d0);  d1 = dpp_add_xor2(d1);
                    lgA[j] += d0;                 lgB[j] += d1;
                    const float e0 = __expf(lgA[j]);
                    const float e1 = __expf(lgB[j]);
                    se0 += e0;                    se1 += e1;
                    s0.x = fmaf(e0, acc[j][0].x, s0.x);  s1.x = fmaf(e1, acc[j][1].x, s1.x);
                    s0.y = fmaf(e0, acc[j][0].y, s0.y);  s1.y = fmaf(e1, acc[j][1].y, s1.y);
                    s0.z = fmaf(e0, acc[j][0].z, s0.z);  s1.z = fmaf(e1, acc[j][1].z, s1.z);
                    s0.w = fmaf(e0, acc[j][0].w, s0.w);  s1.w = fmaf(e1, acc[j][1].w, s1.w);
                }
                // se: og-redundant; lane bits 2-3 on DPP, 4-5 on swizzle
                se0 = dpp_add_shr4(se0);  se1 = dpp_add_shr4(se1);
                se0 = dpp_add_shr8(se0);  se1 = dpp_add_shr8(se1);
                se0 += __shfl_xor(se0, 16, 64);  se1 += __shfl_xor(se1, 16, 64);
                se0 += __shfl_xor(se0, 32, 64);  se1 += __shfl_xor(se1, 32, 64);
                if (lane == 15) { redE[wv][0] = se0; redE[wv][1] = se1; }
            }

            // s-reduce: bits 2-3 via DPP row_shr (og-preserving; totals in
            // lanes 12..15), bits 4-5 via swizzle.
            s0.x = dpp_add_shr4(s0.x);  s1.x = dpp_add_shr4(s1.x);
            s0.y = dpp_add_shr4(s0.y);  s1.y = dpp_add_shr4(s1.y);
            s0.z = dpp_add_shr4(s0.z);  s1.z = dpp_add_shr4(s1.z);
            s0.w = dpp_add_shr4(s0.w);  s1.w = dpp_add_shr4(s1.w);
            s0.x = dpp_add_shr8(s0.x);  s1.x = dpp_add_shr8(s1.x);
            s0.y = dpp_add_shr8(s0.y);  s1.y = dpp_add_shr8(s1.y);
            s0.z = dpp_add_shr8(s0.z);  s1.z = dpp_add_shr8(s1.z);
            s0.w = dpp_add_shr8(s0.w);  s1.w = dpp_add_shr8(s1.w);
            #pragma unroll
            for (int off = 16; off <= 32; off <<= 1) {
                s0.x += __shfl_xor(s0.x, off, 64);  s1.x += __shfl_xor(s1.x, off, 64);
                s0.y += __shfl_xor(s0.y, off, 64);  s1.y += __shfl_xor(s1.y, off, 64);
                s0.z += __shfl_xor(s0.z, off, 64);  s1.z += __shfl_xor(s1.z, off, 64);
                s0.w += __shfl_xor(s0.w, off, 64);  s1.w += __shfl_xor(s1.w, off, 64);
            }
            if (lane >= 12 && lane < 16) {   // lanes 12..15, og = lane&3
                *(float4*)&sRed[wv][0][(lane & 3) * 4] = s0;
                *(float4*)&sRed[wv][1][(lane & 3) * 4] = s1;
            }
            __syncthreads();

            // ---- squash: 64 threads = (sub 0..3, o 0..15)
            if (tid < 64) {
                const int sub = tid >> 4;
                const int o   = tid & 15;
                const int g   = sub >> 1;
                const int l   = sub & 1;
                const float inv = (it == 0)
                    ? (1.0f / (float)R_)
                    : 1.0f / (redE[g * 2][l] + redE[g * 2 + 1][l]);
                float s = (sRed[g * 2][l][o] + sRed[g * 2 + 1][l][o]) * inv;
                float sn = s * s;
                sn = dpp_add_xor1(sn);
                sn = dpp_add_xor2(sn);
                sn += __shfl_xor(sn, 4, 64);
                sn += __shfl_xor(sn, 8, 64);
                const float v = s * (sqrtf(sn) / (1.0f + sn));
                if (it == NITER - 1) {
                    out[((((size_t)(b0C + sub) * C_ + cC) * W_ + pC) * W_ + qC)
                        * COUT + o] = v;
                } else {
                    vS[sub][o] = v;
                }
            }
            if (it == NITER - 1) break;
            __syncthreads();   // vS visible before next iteration
        }

        // advance tile ctx (prefetch for it already in flight)
        xqC = xqN; rwcC = rwcN; pC = pN; qC = qN; b0C = b0N; cC = cN;
    }
}

extern "C" void kernel_launch(void* const* d_in, const int* in_sizes, int n_in,
                              void* d_out, int out_size, void* d_ws, size_t ws_size,
                              hipStream_t stream) {
    const float* x  = (const float*)d_in[0];
    const float* rw = (const float*)d_in[1];
    float* out = (float*)d_out;
    caps_routeF<<<dim3(NBLK), 256, 0, stream>>>(x, rw, out);
}

// Round 16
// 197.128 us; speedup vs baseline: 1.7912x; 1.7912x over previous
//
#include <hip/hip_runtime.h>
#include <math.h>

namespace {
constexpr int NIN   = 32;
constexpr int H_    = 14;
constexpr int CIN   = 8;
constexpr int C_    = 32;
constexpr int COUT  = 16;
constexpr int R_    = 288;
constexpr int W_    = 12;
constexpr int NITER = 3;
constexpr int CH    = 32;              // r per chunk
constexpr int NCH   = 9;               // 288/32
constexpr size_t XSUB = (size_t)NIN * H_ * H_ * CIN;   // x stride per batch elem
}

typedef unsigned int u32;
typedef const __attribute__((address_space(1))) u32* as1_u32p;
typedef __attribute__((address_space(3))) u32* as3_u32p;
typedef float f2 __attribute__((ext_vector_type(2)));

__device__ __forceinline__ void async_copy16(const void* g, void* l) {
    __builtin_amdgcn_global_load_lds((as1_u32p)g, (as3_u32p)l, 16, 0, 0);
}

// Packed fp32 math (VOP3P v_pk_fma_f32 / v_pk_add_f32): 2 fp32 FMAs per
// instruction — R12/R14 post-mortems show VALU issue is the binding pipe
// (VALUBusy 65% with DS cut, time pinned ~155us). Compiler never emits pk
// fp32; inline asm. L-variant broadcasts src0.lo into both lanes, H-variant
// src0.hi (op_sel selects src half for low result, op_sel_hi for high).
// Per-lane IEEE fma, same order as scalar code -> bit-identical results.
#define PKFMA_L(acc, a, b) \
    asm("v_pk_fma_f32 %0, %1, %2, %0 op_sel:[0,0,0] op_sel_hi:[0,1,1]" \
        : "+v"(acc) : "v"(a), "v"(b))
#define PKFMA_H(acc, a, b) \
    asm("v_pk_fma_f32 %0, %1, %2, %0 op_sel:[1,0,0] op_sel_hi:[1,1,1]" \
        : "+v"(acc) : "v"(a), "v"(b))
#define PKADD(acc, a) \
    asm("v_pk_add_f32 %0, %1, %0" : "+v"(acc) : "v"(a))

// VALU-pipe cross-lane ops (DPP) — keep traffic off the DS pipe.
__device__ __forceinline__ float dpp_add_xor1(float v) {
    int t = __builtin_amdgcn_update_dpp(0, __float_as_int(v), 0xB1, 0xF, 0xF, true);
    return v + __int_as_float(t);
}
__device__ __forceinline__ float dpp_add_xor2(float v) {
    int t = __builtin_amdgcn_update_dpp(0, __float_as_int(v), 0x4E, 0xF, 0xF, true);
    return v + __int_as_float(t);
}
__device__ __forceinline__ float dpp_add_shr4(float v) {
    int t = __builtin_amdgcn_update_dpp(0, __float_as_int(v), 0x114, 0xF, 0xF, true);
    return v + __int_as_float(t);
}
__device__ __forceinline__ float dpp_add_shr8(float v) {
    int t = __builtin_amdgcn_update_dpp(0, __float_as_int(v), 0x118, 0xF, 0xF, true);
    return v + __int_as_float(t);
}
template <int CTRL>
__device__ __forceinline__ float dpp_bc(float v) {   // quad broadcast (mov)
    return __int_as_float(
        __builtin_amdgcn_update_dpp(0, __float_as_int(v), CTRL, 0xF, 0xF, true));
}

// One block (256 thr) per (c, b-QUAD, p, q) — R12 structure (153 us best)
// with the FMA-dense loops converted to packed fp32 (v_pk_fma_f32):
// priors 64->32 fma/chunk, routing s-update 16->8 fma/j, iter0 init
// 72->36 adds. Everything else R12 verbatim: W double-buffered via
// global_load_lds (stage(k+1) right after barrier k), x one float4/lane
// + og-quad DPP exchange, s/se reductions bits 2-3 on DPP row_shr,
// 2-barrier routing. Lessons: 256-thr blocks (R6/R10); no forced waves/EU
// (R4); priors fp32 (R2); no persistent-block state (R15: VGPR 256).
__global__ __launch_bounds__(256)
void caps_routeG(const float* __restrict__ x,
                 const float* __restrict__ rw,
                 float* __restrict__ out)
{
    __shared__ float4 wbuf[2][1024];   // [buf][i(8)][cr(32)][og(4)] 16 KB each
    __shared__ float  sRed[4][2][16];  // [wave][local sub][o]
    __shared__ float  redE[4][2];      // [wave][local sub]
    __shared__ float  vS[4][16];       // [sub][o]

    const int tid = threadIdx.x;
    const int p  = blockIdx.x / W_;
    const int q  = blockIdx.x % W_;
    const int b0 = blockIdx.y * 4;
    const int c  = blockIdx.z;

    const int og   = tid & 3;
    const int rl   = tid >> 2;     // 0..63
    const int cr   = rl & 31;      // chunk-local r
    const int sh   = rl >> 5;      // wave-uniform
    const int lane = tid & 63;
    const int wv   = tid >> 6;
    const int sA   = sh * 2;       // first sub of this thread's pair

    // per-lane x base: lane og covers (sub sA + (og>>1), float4-half og&1)
    const float* xq = x + (size_t)(b0 + sA + (og >> 1)) * XSUB + (og & 1) * 4;
    const float4* rwcF4 = (const float4*)(rw + (size_t)c * R_ * CIN * COUT);

    float4 xv;                     // this lane's single x float4 for cur chunk
    auto xld = [&](int k) {
        const int r  = k * CH + cr;
        const int n  = r / 9, rem = r - n * 9;
        const int kh = rem / 3, kw = rem - kh * 3;
        xv = *(const float4*)(xq + ((n * H_ + (p + kh)) * H_ + (q + kw)) * CIN);
    };

    auto stage = [&](int k, int buf) {
        // slot s = t*256+tid -> [ii=s>>7][wcr=(s>>2)&31][wog=s&3];
        // global f4 = wcr*32 + ii*4 + wog (chunk base k*1024 f4)
        const float4* gchunk = rwcF4 + (size_t)k * (CH * 32);
        #pragma unroll
        for (int t = 0; t < 4; ++t) {
            const int s   = t * 256 + tid;
            const int ii  = s >> 7;
            const int wcr = (s >> 2) & 31;
            async_copy16(gchunk + (wcr * 32 + ii * 4 + (s & 3)),
                         (char*)&wbuf[buf][0] + (t * 256 + (tid & 192)) * 16);
        }
    };

    // priors in o-pair form: accP[k][sub][half] = (o components 2h, 2h+1)
    f2 accP[NCH][2][2];

    xld(0);
    stage(0, 0);
    #pragma unroll
    for (int k = 0; k < NCH; ++k) {
        __syncthreads();               // stage(k)+xld(k) drained; other buf free
        if (k + 1 < NCH) stage(k + 1, (k + 1) & 1);
        const float4* wb = &wbuf[k & 1][0];
        // og-quad exchange -> packed channel pairs: chA[j] = (chan2j, chan2j+1)
        const float4 cur = xv;
        f2 chA[4], chB[4];
        chA[0].x = dpp_bc<0x00>(cur.x); chA[0].y = dpp_bc<0x00>(cur.y);
        chA[1].x = dpp_bc<0x00>(cur.z); chA[1].y = dpp_bc<0x00>(cur.w);
        chA[2].x = dpp_bc<0x55>(cur.x); chA[2].y = dpp_bc<0x55>(cur.y);
        chA[3].x = dpp_bc<0x55>(cur.z); chA[3].y = dpp_bc<0x55>(cur.w);
        chB[0].x = dpp_bc<0xAA>(cur.x); chB[0].y = dpp_bc<0xAA>(cur.y);
        chB[1].x = dpp_bc<0xAA>(cur.z); chB[1].y = dpp_bc<0xAA>(cur.w);
        chB[2].x = dpp_bc<0xFF>(cur.x); chB[2].y = dpp_bc<0xFF>(cur.y);
        chB[3].x = dpp_bc<0xFF>(cur.z); chB[3].y = dpp_bc<0xFF>(cur.w);
        if (k + 1 < NCH) xld(k + 1);   // WAR on xv cleared (cur extracted)
        f2 aA0 = {0.f, 0.f}, aA1 = {0.f, 0.f};
        f2 aB0 = {0.f, 0.f}, aB1 = {0.f, 0.f};
        #pragma unroll
        for (int i = 0; i < 8; ++i) {
            const float4 wv4 = wb[i * 128 + cr * 4 + og];   // conflict-free b128
            f2 wxy; wxy.x = wv4.x; wxy.y = wv4.y;
            f2 wzw; wzw.x = wv4.z; wzw.y = wv4.w;
            const f2 xa = chA[i >> 1];
            const f2 xb = chB[i >> 1];
            if (i & 1) {
                PKFMA_H(aA0, xa, wxy);  PKFMA_H(aA1, xa, wzw);
                PKFMA_H(aB0, xb, wxy);  PKFMA_H(aB1, xb, wzw);
            } else {
                PKFMA_L(aA0, xa, wxy);  PKFMA_L(aA1, xa, wzw);
                PKFMA_L(aB0, xb, wxy);  PKFMA_L(aB1, xb, wzw);
            }
        }
        accP[k][0][0] = aA0;  accP[k][0][1] = aA1;
        accP[k][1][0] = aB0;  accP[k][1][1] = aB1;
    }

    float lgA[NCH], lgB[NCH];
    #pragma unroll
    for (int j = 0; j < NCH; ++j) { lgA[j] = 0.f; lgB[j] = 0.f; }

    for (int it = 0; it < NITER; ++it) {
        f2 sA0 = {0.f, 0.f}, sA1 = {0.f, 0.f};
        f2 sB0 = {0.f, 0.f}, sB1 = {0.f, 0.f};
        float se0 = 0.f, se1 = 0.f;

        if (it == 0) {
            #pragma unroll
            for (int j = 0; j < NCH; ++j) {
                PKADD(sA0, accP[j][0][0]);  PKADD(sA1, accP[j][0][1]);
                PKADD(sB0, accP[j][1][0]);  PKADD(sB1, accP[j][1][1]);
            }
        } else {
            const float4 v0 = *(const float4*)&vS[sA][og * 4];
            const float4 v1 = *(const float4*)&vS[sA + 1][og * 4];
            #pragma unroll
            for (int j = 0; j < NCH; ++j) {
                const f2 axy = accP[j][0][0], azw = accP[j][0][1];
                const f2 bxy = accP[j][1][0], bzw = accP[j][1][1];
                float d0 = fmaf(axy.x, v0.x, fmaf(axy.y, v0.y,
                           fmaf(azw.x, v0.z, azw.y * v0.w)));
                float d1 = fmaf(bxy.x, v1.x, fmaf(bxy.y, v1.y,
                           fmaf(bzw.x, v1.z, bzw.y * v1.w)));
                d0 = dpp_add_xor1(d0);  d1 = dpp_add_xor1(d1);   // VALU
                d0 = dpp_add_xor2(d0);  d1 = dpp_add_xor2(d1);
                lgA[j] += d0;                 lgB[j] += d1;
                const float e0 = __expf(lgA[j]);
                const float e1 = __expf(lgB[j]);
                se0 += e0;                    se1 += e1;
                f2 ep; ep.x = e0; ep.y = e1;
                PKFMA_L(sA0, ep, axy);  PKFMA_L(sA1, ep, azw);
                PKFMA_H(sB0, ep, bxy);  PKFMA_H(sB1, ep, bzw);
            }
            // se: og-redundant; lane bits 2-3 on DPP, 4-5 on swizzle
            se0 = dpp_add_shr4(se0);  se1 = dpp_add_shr4(se1);
            se0 = dpp_add_shr8(se0);  se1 = dpp_add_shr8(se1);
            se0 += __shfl_xor(se0, 16, 64);  se1 += __shfl_xor(se1, 16, 64);
            se0 += __shfl_xor(se0, 32, 64);  se1 += __shfl_xor(se1, 32, 64);
            if (lane == 15) { redE[wv][0] = se0; redE[wv][1] = se1; }
        }

        // unpack to scalars for the cross-lane reduction (register renaming)
        float4 s0 = make_float4(sA0.x, sA0.y, sA1.x, sA1.y);
        float4 s1 = make_float4(sB0.x, sB0.y, sB1.x, sB1.y);

        // s-reduce: bits 2-3 via DPP row_shr (og-preserving; totals in lanes
        // 12..15), bits 4-5 via swizzle.
        s0.x = dpp_add_shr4(s0.x);  s1.x = dpp_add_shr4(s1.x);
        s0.y = dpp_add_shr4(s0.y);  s1.y = dpp_add_shr4(s1.y);
        s0.z = dpp_add_shr4(s0.z);  s1.z = dpp_add_shr4(s1.z);
        s0.w = dpp_add_shr4(s0.w);  s1.w = dpp_add_shr4(s1.w);
        s0.x = dpp_add_shr8(s0.x);  s1.x = dpp_add_shr8(s1.x);
        s0.y = dpp_add_shr8(s0.y);  s1.y = dpp_add_shr8(s1.y);
        s0.z = dpp_add_shr8(s0.z);  s1.z = dpp_add_shr8(s1.z);
        s0.w = dpp_add_shr8(s0.w);  s1.w = dpp_add_shr8(s1.w);
        #pragma unroll
        for (int off = 16; off <= 32; off <<= 1) {
            s0.x += __shfl_xor(s0.x, off, 64);  s1.x += __shfl_xor(s1.x, off, 64);
            s0.y += __shfl_xor(s0.y, off, 64);  s1.y += __shfl_xor(s1.y, off, 64);
            s0.z += __shfl_xor(s0.z, off, 64);  s1.z += __shfl_xor(s1.z, off, 64);
            s0.w += __shfl_xor(s0.w, off, 64);  s1.w += __shfl_xor(s1.w, off, 64);
        }
        if (lane >= 12 && lane < 16) {   // lanes 12..15, og = lane&3
            *(float4*)&sRed[wv][0][(lane & 3) * 4] = s0;
            *(float4*)&sRed[wv][1][(lane & 3) * 4] = s1;
        }
        __syncthreads();

        // ---- squash: 64 threads = (sub 0..3, o 0..15)
        if (tid < 64) {
            const int sub = tid >> 4;
            const int o   = tid & 15;
            const int g   = sub >> 1;      // wave-pair group
            const int l   = sub & 1;       // local sub within pair
            const float inv = (it == 0)
                ? (1.0f / (float)R_)
                : 1.0f / (redE[g * 2][l] + redE[g * 2 + 1][l]);
            float s = (sRed[g * 2][l][o] + sRed[g * 2 + 1][l][o]) * inv;
            float sn = s * s;
            sn = dpp_add_xor1(sn);
            sn = dpp_add_xor2(sn);
            sn += __shfl_xor(sn, 4, 64);
            sn += __shfl_xor(sn, 8, 64);
            const float v = s * (sqrtf(sn) / (1.0f + sn));
            if (it == NITER - 1) {
                out[((((size_t)(b0 + sub) * C_ + c) * W_ + p) * W_ + q) * COUT + o] = v;
            } else {
                vS[sub][o] = v;
            }
        }
        if (it == NITER - 1) break;
        __syncthreads();   // vS visible before next iteration
    }
}

extern "C" void kernel_launch(void* const* d_in, const int* in_sizes, int n_in,
                              void* d_out, int out_size, void* d_ws, size_t ws_size,
                              hipStream_t stream) {
    const float* x  = (const float*)d_in[0];
    const float* rw = (const float*)d_in[1];
    float* out = (float*)d_out;
    dim3 grid(W_ * W_, 2, C_);
    caps_routeG<<<grid, 256, 0, stream>>>(x, rw, out);
}